// Round 1
// baseline (1149.271 us; speedup 1.0000x reference)
//
#include <hip/hip_runtime.h>
#include <stdint.h>

#define N_NODES 100000
#define N_EDGES 3200000
#define N_GRAPHS 512
#define DIM 128
#define M_PAD 100096          // N_NODES padded to multiple of 64
#define SCAN_NB 49            // 49 * 2048 = 100352 >= 100001
#define SCAN_PAD 100352

typedef __bf16 bf16x8 __attribute__((ext_vector_type(8)));
typedef float f32x4 __attribute__((ext_vector_type(4)));

__device__ __forceinline__ unsigned short f2bf(float f) {
  unsigned u = __float_as_uint(f);
  u = u + 0x7FFFu + ((u >> 16) & 1u);      // round-to-nearest-even
  return (unsigned short)(u >> 16);
}
__device__ __forceinline__ float bflo(unsigned v) { return __uint_as_float(v << 16); }
__device__ __forceinline__ float bfhi(unsigned v) { return __uint_as_float(v & 0xFFFF0000u); }
__device__ __forceinline__ unsigned packbf(float a, float b) {
  return (unsigned)f2bf(a) | ((unsigned)f2bf(b) << 16);
}

// ---------------- CSR build ----------------
__global__ void k_zero32(int* __restrict__ p, int n) {
  int i = blockIdx.x * 256 + threadIdx.x;
  if (i < n) p[i] = 0;
}

__global__ void k_count(const int* __restrict__ ei, int* __restrict__ deg) {
  int e = blockIdx.x * 256 + threadIdx.x;
  if (e < N_EDGES) atomicAdd(&deg[ei[N_EDGES + e]], 1);
}

__global__ void k_scan1(const int* __restrict__ deg, int* __restrict__ bsum) {
  __shared__ int lds[256];
  int t = threadIdx.x;
  int base = blockIdx.x * 2048 + t * 8;
  int s = 0;
#pragma unroll
  for (int j = 0; j < 8; ++j) s += deg[base + j];
  lds[t] = s; __syncthreads();
  for (int off = 128; off > 0; off >>= 1) {
    if (t < off) lds[t] += lds[t + off];
    __syncthreads();
  }
  if (t == 0) bsum[blockIdx.x] = lds[0];
}

__global__ void k_scan2(const int* __restrict__ bsum, int* __restrict__ boff) {
  if (threadIdx.x == 0) {
    int run = 0;
    for (int i = 0; i < SCAN_NB; ++i) { int v = bsum[i]; boff[i] = run; run += v; }
  }
}

__global__ void k_scan3(const int* __restrict__ deg, const int* __restrict__ boff,
                        int* __restrict__ row_ptr, int* __restrict__ cursor) {
  __shared__ int lds[256];
  int t = threadIdx.x;
  int base = blockIdx.x * 2048 + t * 8;
  int v[8]; int s = 0;
#pragma unroll
  for (int j = 0; j < 8; ++j) { v[j] = deg[base + j]; s += v[j]; }
  lds[t] = s; __syncthreads();
  for (int off = 1; off < 256; off <<= 1) {
    int x = 0;
    if (t >= off) x = lds[t - off];
    __syncthreads();
    lds[t] += x;
    __syncthreads();
  }
  int run = boff[blockIdx.x] + lds[t] - s;   // exclusive prefix for this thread
#pragma unroll
  for (int j = 0; j < 8; ++j) {
    int idx = base + j;
    if (idx <= N_NODES) {
      row_ptr[idx] = run;
      if (idx < N_NODES) cursor[idx] = run;
    }
    run += v[j];
  }
}

__global__ void k_fill(const int* __restrict__ ei, int* __restrict__ cursor,
                       int* __restrict__ col) {
  int e = blockIdx.x * 256 + threadIdx.x;
  if (e < N_EDGES) {
    int d = ei[N_EDGES + e];
    int pos = atomicAdd(&cursor[d], 1);
    col[pos] = ei[e];
  }
}

__global__ void k_gptr(const int* __restrict__ batch, int* __restrict__ gptr) {
  int g = blockIdx.x * 64 + threadIdx.x;
  if (g > N_GRAPHS) return;
  int lo = 0, hi = N_NODES;
  while (lo < hi) { int mid = (lo + hi) >> 1; if (batch[mid] < g) lo = mid + 1; else hi = mid; }
  gptr[g] = lo;
}

// ---------------- conversions / coefficients ----------------
__global__ void k_convx(const float* __restrict__ x, unsigned* __restrict__ h0) {
  int i = blockIdx.x * 256 + threadIdx.x;   // over M_PAD*64 uint (2 bf16 each)
  if (i >= M_PAD * 64) return;
  unsigned v = 0;
  if ((i >> 6) < N_NODES) {
    float2 f = ((const float2*)x)[i];
    v = packbf(f.x, f.y);
  }
  h0[i] = v;
}

__global__ void k_convw(const float* __restrict__ W1, const float* __restrict__ W2,
                        unsigned short* __restrict__ Wt1, unsigned short* __restrict__ Wt2) {
  int i = blockIdx.x * 256 + threadIdx.x;
  if (i >= 3 * DIM * DIM) return;
  int l = i >> 14, rem = i & 16383, k = rem >> 7, n = rem & 127;
  int o = (l << 14) + (n << 7) + k;          // transposed: Wt[l][n][k]
  Wt1[o] = f2bf(W1[i]);
  Wt2[o] = f2bf(W2[i]);
}

__global__ void k_coef(const float* __restrict__ b1, const float* __restrict__ gamma,
                       const float* __restrict__ beta, const float* __restrict__ rmean,
                       const float* __restrict__ rvar, const float* __restrict__ b2,
                       float* __restrict__ sA1, float* __restrict__ sB1,
                       float* __restrict__ sA2, float* __restrict__ sB2) {
  int i = blockIdx.x * 128 + threadIdx.x;
  if (i >= 3 * DIM) return;
  float sa = gamma[i] * rsqrtf(rvar[i] + 1e-5f);
  sA1[i] = sa;
  sB1[i] = fmaf(sa, b1[i] - rmean[i], beta[i]);  // sa*(b1-rmean)+beta
  sA2[i] = 1.0f;
  sB2[i] = b2[i];
}

// ---------------- aggregation: tmp = h + sum_{nbr} h[nbr]  (wave per node) ----------------
__global__ __launch_bounds__(256) void k_aggr(const unsigned* __restrict__ h,
                                              const int* __restrict__ row_ptr,
                                              const int* __restrict__ col,
                                              unsigned* __restrict__ tmp) {
  int wv = (blockIdx.x << 2) + (threadIdx.x >> 6);
  int lane = threadIdx.x & 63;
  if (wv >= M_PAD) return;
  if (wv >= N_NODES) { tmp[wv * 64 + lane] = 0u; return; }
  unsigned self = h[wv * 64 + lane];
  float a0 = bflo(self), a1 = bfhi(self);
  int s = __builtin_amdgcn_readfirstlane(row_ptr[wv]);
  int e = __builtin_amdgcn_readfirstlane(row_ptr[wv + 1]);
  int i = s;
  for (; i + 4 <= e; i += 4) {
    int c0 = __builtin_amdgcn_readfirstlane(col[i]);
    int c1 = __builtin_amdgcn_readfirstlane(col[i + 1]);
    int c2 = __builtin_amdgcn_readfirstlane(col[i + 2]);
    int c3 = __builtin_amdgcn_readfirstlane(col[i + 3]);
    unsigned v0 = h[c0 * 64 + lane];
    unsigned v1 = h[c1 * 64 + lane];
    unsigned v2 = h[c2 * 64 + lane];
    unsigned v3 = h[c3 * 64 + lane];
    a0 += bflo(v0) + bflo(v1) + bflo(v2) + bflo(v3);
    a1 += bfhi(v0) + bfhi(v1) + bfhi(v2) + bfhi(v3);
  }
  for (; i < e; ++i) {
    int c = __builtin_amdgcn_readfirstlane(col[i]);
    unsigned v = h[c * 64 + lane];
    a0 += bflo(v); a1 += bfhi(v);
  }
  tmp[wv * 64 + lane] = packbf(a0, a1);
}

// ---------------- GEMM: out = relu(sA[col] * (A @ W) + sB[col]) in bf16 ----------------
// A: [M_PAD][128] bf16 row-major.  Wt: [128][128] bf16, TRANSPOSED (Wt[n][k] = W[k][n]).
// block = 256 thr = 4 waves; wave w -> rows [blk*64 + w*16, +16), all 128 cols.
__global__ __launch_bounds__(256) void k_gemm(const unsigned short* __restrict__ A,
                                              const unsigned short* __restrict__ Wt,
                                              const float* __restrict__ sA,
                                              const float* __restrict__ sB,
                                              unsigned short* __restrict__ out) {
  int w = threadIdx.x >> 6, lane = threadIdx.x & 63;
  int q = lane >> 4, n16 = lane & 15;
  int r0 = (blockIdx.x << 6) + (w << 4);
  f32x4 acc[8] = {};
#pragma unroll
  for (int ks = 0; ks < 4; ++ks) {
    // A frag: A[m = lane&15][k = ks*32 + q*8 + j]
    bf16x8 a = *(const bf16x8*)(A + (size_t)(r0 + n16) * DIM + ks * 32 + q * 8);
#pragma unroll
    for (int c = 0; c < 8; ++c) {
      // B frag: B[k][n] = Wt[n][k], n = c*16 + lane&15, k = ks*32 + q*8 + j
      bf16x8 b = *(const bf16x8*)(Wt + (size_t)((c << 4) + n16) * DIM + ks * 32 + q * 8);
      acc[c] = __builtin_amdgcn_mfma_f32_16x16x32_bf16(a, b, acc[c], 0, 0, 0);
    }
  }
#pragma unroll
  for (int c = 0; c < 8; ++c) {
    int colc = (c << 4) + n16;
    float s = sA[colc], t = sB[colc];
#pragma unroll
    for (int r = 0; r < 4; ++r) {
      // C/D: row = q*4 + r, col = lane&15 (verified m89/m91 mapping)
      float v = fmaf(s, acc[c][r], t);
      v = fmaxf(v, 0.0f);
      out[(size_t)(r0 + (q << 2) + r) * DIM + colc] = f2bf(v);
    }
  }
}

// ---------------- pooling: pooled[g][l*128+t] = sum_{rows of graph g} h[row][t] ----------------
__global__ __launch_bounds__(512) void k_pool(const unsigned short* __restrict__ h,
                                              const int* __restrict__ gptr,
                                              float* __restrict__ pooled, int layer) {
  __shared__ float red[4][DIM];
  int g = blockIdx.x;
  int t = threadIdx.x & 127, s4 = threadIdx.x >> 7;
  int beg = gptr[g], end = gptr[g + 1];
  float acc = 0.f;
  for (int r = beg + s4; r < end; r += 4)
    acc += __uint_as_float(((unsigned)h[(size_t)r * DIM + t]) << 16);
  red[s4][t] = acc; __syncthreads();
  if (s4 == 0)
    pooled[g * 384 + layer * DIM + t] = red[0][t] + red[1][t] + red[2][t] + red[3][t];
}

// ---------------- head: relu(pooled @ Wfin + bfin) @ Wout + bout, log_softmax ----------------
__global__ __launch_bounds__(128) void k_head(const float* __restrict__ pooled,
                                              const float* __restrict__ Wfin,
                                              const float* __restrict__ bfin,
                                              const float* __restrict__ Wout,
                                              const float* __restrict__ bout,
                                              float* __restrict__ out) {
  __shared__ float p[384], hf[384], lg[10];
  __shared__ float lse;
  int g = blockIdx.x, t = threadIdx.x;
  p[t] = pooled[g * 384 + t];
  p[t + 128] = pooled[g * 384 + 128 + t];
  p[t + 256] = pooled[g * 384 + 256 + t];
  __syncthreads();
#pragma unroll
  for (int jj = 0; jj < 3; ++jj) {
    int j = t + jj * 128;
    float acc = bfin[j];
    for (int k = 0; k < 384; ++k) acc = fmaf(p[k], Wfin[k * 384 + j], acc);
    hf[j] = fmaxf(acc, 0.f);
  }
  __syncthreads();
  if (t < 10) {
    float acc = bout[t];
    for (int k = 0; k < 384; ++k) acc = fmaf(hf[k], Wout[k * 10 + t], acc);
    lg[t] = acc;
  }
  __syncthreads();
  if (t == 0) {
    float m = lg[0];
    for (int i = 1; i < 10; ++i) m = fmaxf(m, lg[i]);
    float ss = 0.f;
    for (int i = 0; i < 10; ++i) ss += expf(lg[i] - m);
    lse = m + logf(ss);
  }
  __syncthreads();
  if (t < 10) {
    out[g * 10 + t] = lg[t];
    out[N_GRAPHS * 10 + g * 10 + t] = lg[t] - lse;
  }
}

extern "C" void kernel_launch(void* const* d_in, const int* in_sizes, int n_in,
                              void* d_out, int out_size, void* d_ws, size_t ws_size,
                              hipStream_t stream) {
  const float* x     = (const float*)d_in[0];
  const int*   ei    = (const int*)d_in[1];    // [2, N_EDGES]: src then dst
  const int*   batch = (const int*)d_in[2];
  const float* W1    = (const float*)d_in[4];
  const float* b1    = (const float*)d_in[5];
  const float* gamma = (const float*)d_in[6];
  const float* beta  = (const float*)d_in[7];
  const float* rmean = (const float*)d_in[8];
  const float* rvar  = (const float*)d_in[9];
  const float* W2    = (const float*)d_in[10];
  const float* b2    = (const float*)d_in[11];
  const float* Wfin  = (const float*)d_in[12];
  const float* bfin  = (const float*)d_in[13];
  const float* Wout  = (const float*)d_in[14];
  const float* bout  = (const float*)d_in[15];
  float* out = (float*)d_out;

  char* p = (char*)d_ws;
  auto alloc = [&](size_t bytes) { char* r = p; p += (bytes + 255) & ~255ull; return r; };
  int* deg      = (int*)alloc(SCAN_PAD * 4);
  int* row_ptr  = (int*)alloc((N_NODES + 1) * 4);
  int* cursor   = (int*)alloc((size_t)N_NODES * 4);
  int* bsum     = (int*)alloc(SCAN_NB * 4);
  int* boff     = (int*)alloc(SCAN_NB * 4);
  int* colb     = (int*)alloc((size_t)N_EDGES * 4);
  int* gptr     = (int*)alloc((N_GRAPHS + 1) * 4);
  unsigned short* hA  = (unsigned short*)alloc((size_t)M_PAD * DIM * 2);
  unsigned short* hB  = (unsigned short*)alloc((size_t)M_PAD * DIM * 2);
  unsigned short* tmp = (unsigned short*)alloc((size_t)M_PAD * DIM * 2);
  unsigned short* zb  = (unsigned short*)alloc((size_t)M_PAD * DIM * 2);
  unsigned short* Wt1 = (unsigned short*)alloc(3 * DIM * DIM * 2);
  unsigned short* Wt2 = (unsigned short*)alloc(3 * DIM * DIM * 2);
  float* sA1    = (float*)alloc(384 * 4);
  float* sB1    = (float*)alloc(384 * 4);
  float* sA2    = (float*)alloc(384 * 4);
  float* sB2    = (float*)alloc(384 * 4);
  float* pooled = (float*)alloc((size_t)N_GRAPHS * 384 * 4);

  // CSR build (edges constant across layers -> once per launch)
  k_zero32<<<(SCAN_PAD + 255) / 256, 256, 0, stream>>>(deg, SCAN_PAD);
  k_count<<<(N_EDGES + 255) / 256, 256, 0, stream>>>(ei, deg);
  k_scan1<<<SCAN_NB, 256, 0, stream>>>(deg, bsum);
  k_scan2<<<1, 64, 0, stream>>>(bsum, boff);
  k_scan3<<<SCAN_NB, 256, 0, stream>>>(deg, boff, row_ptr, cursor);
  k_fill<<<(N_EDGES + 255) / 256, 256, 0, stream>>>(ei, cursor, colb);
  k_gptr<<<9, 64, 0, stream>>>(batch, gptr);

  k_convx<<<(M_PAD * 64 + 255) / 256, 256, 0, stream>>>(x, (unsigned*)hA);
  k_convw<<<(3 * DIM * DIM + 255) / 256, 256, 0, stream>>>(W1, W2, Wt1, Wt2);
  k_coef<<<3, 128, 0, stream>>>(b1, gamma, beta, rmean, rvar, b2, sA1, sB1, sA2, sB2);

  unsigned short* hc = hA;
  unsigned short* hn = hB;
  for (int l = 0; l < 3; ++l) {
    k_aggr<<<M_PAD / 4, 256, 0, stream>>>((const unsigned*)hc, row_ptr, colb, (unsigned*)tmp);
    k_gemm<<<M_PAD / 64, 256, 0, stream>>>(tmp, Wt1 + l * DIM * DIM, sA1 + l * DIM, sB1 + l * DIM, zb);
    k_gemm<<<M_PAD / 64, 256, 0, stream>>>(zb, Wt2 + l * DIM * DIM, sA2 + l * DIM, sB2 + l * DIM, hn);
    k_pool<<<N_GRAPHS, 512, 0, stream>>>(hn, gptr, pooled, l);
    unsigned short* t2 = hc; hc = hn; hn = t2;
  }
  k_head<<<N_GRAPHS, 128, 0, stream>>>(pooled, Wfin, bfin, Wout, bout, out);
}

// Round 2
// 1120.648 us; speedup vs baseline: 1.0255x; 1.0255x over previous
//
#include <hip/hip_runtime.h>
#include <stdint.h>

#define N_NODES 100000
#define N_EDGES 3200000
#define N_GRAPHS 512
#define DIM 128
#define M_PAD 100096          // N_NODES padded to multiple of 64
#define NBUCK 391             // buckets of 256 dst nodes: 391*256 = 100096 >= 100000
#define NCOPY 8               // per-XCD-ish copies (blockIdx & 7)
#define CAP 1536              // capacity per (copy,bucket); mean ~1023, sigma ~32

typedef __bf16 bf16x8 __attribute__((ext_vector_type(8)));
typedef float f32x4 __attribute__((ext_vector_type(4)));

__device__ __forceinline__ unsigned short f2bf(float f) {
  unsigned u = __float_as_uint(f);
  u = u + 0x7FFFu + ((u >> 16) & 1u);      // round-to-nearest-even
  return (unsigned short)(u >> 16);
}
__device__ __forceinline__ float bflo(unsigned v) { return __uint_as_float(v << 16); }
__device__ __forceinline__ float bfhi(unsigned v) { return __uint_as_float(v & 0xFFFF0000u); }
__device__ __forceinline__ unsigned packbf(float a, float b) {
  return (unsigned)f2bf(a) | ((unsigned)f2bf(b) << 16);
}

// ---------------- CSR build: bucketed two-pass counting sort ----------------
__global__ void k_zero32(int* __restrict__ p, int n) {
  int i = blockIdx.x * 256 + threadIdx.x;
  if (i < n) p[i] = 0;
}

// Pass A: scatter edges into (copy,bucket) record arrays. Record = (src<<8)|dst_local.
__global__ __launch_bounds__(256) void k_bucket(const int* __restrict__ ei,
                                                int* __restrict__ cnt,
                                                unsigned* __restrict__ rec) {
  int e = blockIdx.x * 256 + threadIdx.x;
  if (e >= N_EDGES) return;
  int copy = blockIdx.x & (NCOPY - 1);
  int d = ei[N_EDGES + e];
  int s = ei[e];
  int b = d >> 8;
  int slot = atomicAdd(&cnt[copy * NBUCK + b], 1);
  if (slot < CAP)
    rec[(size_t)(copy * NBUCK + b) * CAP + slot] = ((unsigned)s << 8) | (unsigned)(d & 255);
}

// Scan bucket totals -> bucket bases. One block of 512 threads.
__global__ __launch_bounds__(512) void k_bscan(const int* __restrict__ cnt,
                                               int* __restrict__ bbase,
                                               int* __restrict__ row_ptr) {
  __shared__ int sc[512];
  int t = threadIdx.x;
  int tot = 0;
  if (t < NBUCK) {
#pragma unroll
    for (int r = 0; r < NCOPY; ++r) tot += min(cnt[r * NBUCK + t], CAP);
  }
  sc[t] = tot; __syncthreads();
  for (int off = 1; off < 512; off <<= 1) {
    int x = (t >= off) ? sc[t - off] : 0;
    __syncthreads();
    sc[t] += x;
    __syncthreads();
  }
  if (t < NBUCK) bbase[t] = sc[t] - tot;                 // exclusive
  if (t == NBUCK - 1) {
    bbase[NBUCK] = sc[t];
    row_ptr[N_NODES] = sc[t];                            // == N_EDGES when no drops
  }
}

// Pass B: per bucket -> LDS histogram + scan -> row_ptr slice + col scatter (LDS atomics).
__global__ __launch_bounds__(256) void k_build(const unsigned* __restrict__ rec,
                                               const int* __restrict__ cnt,
                                               const int* __restrict__ bbase,
                                               int* __restrict__ row_ptr,
                                               int* __restrict__ col) {
  __shared__ int hist[256];
  __shared__ int sc[256];
  __shared__ int curs[256];
  int b = blockIdx.x, t = threadIdx.x;
  hist[t] = 0; __syncthreads();
#pragma unroll
  for (int r = 0; r < NCOPY; ++r) {
    int n = min(cnt[r * NBUCK + b], CAP);
    const unsigned* p = rec + (size_t)(r * NBUCK + b) * CAP;
    for (int i = t; i < n; i += 256) atomicAdd(&hist[p[i] & 255u], 1);
  }
  __syncthreads();
  int v = hist[t];
  sc[t] = v; __syncthreads();
  for (int off = 1; off < 256; off <<= 1) {
    int x = (t >= off) ? sc[t - off] : 0;
    __syncthreads();
    sc[t] += x;
    __syncthreads();
  }
  int excl = bbase[b] + sc[t] - v;
  int node = (b << 8) + t;
  if (node < N_NODES) row_ptr[node] = excl;
  curs[t] = excl;
  __syncthreads();
#pragma unroll
  for (int r = 0; r < NCOPY; ++r) {
    int n = min(cnt[r * NBUCK + b], CAP);
    const unsigned* p = rec + (size_t)(r * NBUCK + b) * CAP;
    for (int i = t; i < n; i += 256) {
      unsigned w = p[i];
      int pos = atomicAdd(&curs[w & 255u], 1);
      col[pos] = (int)(w >> 8);
    }
  }
}

__global__ void k_gptr(const int* __restrict__ batch, int* __restrict__ gptr) {
  int g = blockIdx.x * 64 + threadIdx.x;
  if (g > N_GRAPHS) return;
  int lo = 0, hi = N_NODES;
  while (lo < hi) { int mid = (lo + hi) >> 1; if (batch[mid] < g) lo = mid + 1; else hi = mid; }
  gptr[g] = lo;
}

// ---------------- conversions / coefficients ----------------
__global__ void k_convx(const float* __restrict__ x, unsigned* __restrict__ h0) {
  int i = blockIdx.x * 256 + threadIdx.x;   // over M_PAD*64 uint (2 bf16 each)
  if (i >= M_PAD * 64) return;
  unsigned v = 0;
  if ((i >> 6) < N_NODES) {
    float2 f = ((const float2*)x)[i];
    v = packbf(f.x, f.y);
  }
  h0[i] = v;
}

__global__ void k_convw(const float* __restrict__ W1, const float* __restrict__ W2,
                        unsigned short* __restrict__ Wt1, unsigned short* __restrict__ Wt2) {
  int i = blockIdx.x * 256 + threadIdx.x;
  if (i >= 3 * DIM * DIM) return;
  int l = i >> 14, rem = i & 16383, k = rem >> 7, n = rem & 127;
  int o = (l << 14) + (n << 7) + k;          // transposed: Wt[l][n][k]
  Wt1[o] = f2bf(W1[i]);
  Wt2[o] = f2bf(W2[i]);
}

__global__ void k_coef(const float* __restrict__ b1, const float* __restrict__ gamma,
                       const float* __restrict__ beta, const float* __restrict__ rmean,
                       const float* __restrict__ rvar, const float* __restrict__ b2,
                       float* __restrict__ sA1, float* __restrict__ sB1,
                       float* __restrict__ sA2, float* __restrict__ sB2) {
  int i = blockIdx.x * 128 + threadIdx.x;
  if (i >= 3 * DIM) return;
  float sa = gamma[i] * rsqrtf(rvar[i] + 1e-5f);
  sA1[i] = sa;
  sB1[i] = fmaf(sa, b1[i] - rmean[i], beta[i]);  // sa*(b1-rmean)+beta
  sA2[i] = 1.0f;
  sB2[i] = b2[i];
}

// ---------------- aggregation: tmp = h + sum_{nbr} h[nbr]  (wave per node) ----------------
__global__ __launch_bounds__(256) void k_aggr(const unsigned* __restrict__ h,
                                              const int* __restrict__ row_ptr,
                                              const int* __restrict__ col,
                                              unsigned* __restrict__ tmp) {
  int wv = (blockIdx.x << 2) + (threadIdx.x >> 6);
  int lane = threadIdx.x & 63;
  if (wv >= M_PAD) return;
  if (wv >= N_NODES) { tmp[wv * 64 + lane] = 0u; return; }
  unsigned self = h[wv * 64 + lane];
  float a0 = bflo(self), a1 = bfhi(self);
  int s = __builtin_amdgcn_readfirstlane(row_ptr[wv]);
  int e = __builtin_amdgcn_readfirstlane(row_ptr[wv + 1]);
  int i = s;
  for (; i + 4 <= e; i += 4) {
    int c0 = __builtin_amdgcn_readfirstlane(col[i]);
    int c1 = __builtin_amdgcn_readfirstlane(col[i + 1]);
    int c2 = __builtin_amdgcn_readfirstlane(col[i + 2]);
    int c3 = __builtin_amdgcn_readfirstlane(col[i + 3]);
    unsigned v0 = h[c0 * 64 + lane];
    unsigned v1 = h[c1 * 64 + lane];
    unsigned v2 = h[c2 * 64 + lane];
    unsigned v3 = h[c3 * 64 + lane];
    a0 += bflo(v0) + bflo(v1) + bflo(v2) + bflo(v3);
    a1 += bfhi(v0) + bfhi(v1) + bfhi(v2) + bfhi(v3);
  }
  for (; i < e; ++i) {
    int c = __builtin_amdgcn_readfirstlane(col[i]);
    unsigned v = h[c * 64 + lane];
    a0 += bflo(v); a1 += bfhi(v);
  }
  tmp[wv * 64 + lane] = packbf(a0, a1);
}

// ---------------- GEMM: out = relu(sA[col] * (A @ W) + sB[col]) in bf16 ----------------
__global__ __launch_bounds__(256) void k_gemm(const unsigned short* __restrict__ A,
                                              const unsigned short* __restrict__ Wt,
                                              const float* __restrict__ sA,
                                              const float* __restrict__ sB,
                                              unsigned short* __restrict__ out) {
  int w = threadIdx.x >> 6, lane = threadIdx.x & 63;
  int q = lane >> 4, n16 = lane & 15;
  int r0 = (blockIdx.x << 6) + (w << 4);
  f32x4 acc[8] = {};
#pragma unroll
  for (int ks = 0; ks < 4; ++ks) {
    bf16x8 a = *(const bf16x8*)(A + (size_t)(r0 + n16) * DIM + ks * 32 + q * 8);
#pragma unroll
    for (int c = 0; c < 8; ++c) {
      bf16x8 b = *(const bf16x8*)(Wt + (size_t)((c << 4) + n16) * DIM + ks * 32 + q * 8);
      acc[c] = __builtin_amdgcn_mfma_f32_16x16x32_bf16(a, b, acc[c], 0, 0, 0);
    }
  }
#pragma unroll
  for (int c = 0; c < 8; ++c) {
    int colc = (c << 4) + n16;
    float s = sA[colc], t = sB[colc];
#pragma unroll
    for (int r = 0; r < 4; ++r) {
      float v = fmaf(s, acc[c][r], t);
      v = fmaxf(v, 0.0f);
      out[(size_t)(r0 + (q << 2) + r) * DIM + colc] = f2bf(v);
    }
  }
}

// ---------------- pooling ----------------
__global__ __launch_bounds__(512) void k_pool(const unsigned short* __restrict__ h,
                                              const int* __restrict__ gptr,
                                              float* __restrict__ pooled, int layer) {
  __shared__ float red[4][DIM];
  int g = blockIdx.x;
  int t = threadIdx.x & 127, s4 = threadIdx.x >> 7;
  int beg = gptr[g], end = gptr[g + 1];
  float acc = 0.f;
  for (int r = beg + s4; r < end; r += 4)
    acc += __uint_as_float(((unsigned)h[(size_t)r * DIM + t]) << 16);
  red[s4][t] = acc; __syncthreads();
  if (s4 == 0)
    pooled[g * 384 + layer * DIM + t] = red[0][t] + red[1][t] + red[2][t] + red[3][t];
}

// ---------------- head ----------------
__global__ __launch_bounds__(128) void k_head(const float* __restrict__ pooled,
                                              const float* __restrict__ Wfin,
                                              const float* __restrict__ bfin,
                                              const float* __restrict__ Wout,
                                              const float* __restrict__ bout,
                                              float* __restrict__ out) {
  __shared__ float p[384], hf[384], lg[10];
  __shared__ float lse;
  int g = blockIdx.x, t = threadIdx.x;
  p[t] = pooled[g * 384 + t];
  p[t + 128] = pooled[g * 384 + 128 + t];
  p[t + 256] = pooled[g * 384 + 256 + t];
  __syncthreads();
#pragma unroll
  for (int jj = 0; jj < 3; ++jj) {
    int j = t + jj * 128;
    float acc = bfin[j];
    for (int k = 0; k < 384; ++k) acc = fmaf(p[k], Wfin[k * 384 + j], acc);
    hf[j] = fmaxf(acc, 0.f);
  }
  __syncthreads();
  if (t < 10) {
    float acc = bout[t];
    for (int k = 0; k < 384; ++k) acc = fmaf(hf[k], Wout[k * 10 + t], acc);
    lg[t] = acc;
  }
  __syncthreads();
  if (t == 0) {
    float m = lg[0];
    for (int i = 1; i < 10; ++i) m = fmaxf(m, lg[i]);
    float ss = 0.f;
    for (int i = 0; i < 10; ++i) ss += expf(lg[i] - m);
    lse = m + logf(ss);
  }
  __syncthreads();
  if (t < 10) {
    out[g * 10 + t] = lg[t];
    out[N_GRAPHS * 10 + g * 10 + t] = lg[t] - lse;
  }
}

extern "C" void kernel_launch(void* const* d_in, const int* in_sizes, int n_in,
                              void* d_out, int out_size, void* d_ws, size_t ws_size,
                              hipStream_t stream) {
  const float* x     = (const float*)d_in[0];
  const int*   ei    = (const int*)d_in[1];    // [2, N_EDGES]: src then dst
  const int*   batch = (const int*)d_in[2];
  const float* W1    = (const float*)d_in[4];
  const float* b1    = (const float*)d_in[5];
  const float* gamma = (const float*)d_in[6];
  const float* beta  = (const float*)d_in[7];
  const float* rmean = (const float*)d_in[8];
  const float* rvar  = (const float*)d_in[9];
  const float* W2    = (const float*)d_in[10];
  const float* b2    = (const float*)d_in[11];
  const float* Wfin  = (const float*)d_in[12];
  const float* bfin  = (const float*)d_in[13];
  const float* Wout  = (const float*)d_in[14];
  const float* bout  = (const float*)d_in[15];
  float* out = (float*)d_out;

  char* p = (char*)d_ws;
  auto alloc = [&](size_t bytes) { char* r = p; p += (bytes + 255) & ~255ull; return r; };
  int* cnt      = (int*)alloc((size_t)NCOPY * NBUCK * 4);
  unsigned* rec = (unsigned*)alloc((size_t)NCOPY * NBUCK * CAP * 4);
  int* bbase    = (int*)alloc((NBUCK + 1) * 4);
  int* row_ptr  = (int*)alloc((N_NODES + 1) * 4);
  int* colb     = (int*)alloc((size_t)N_EDGES * 4);
  int* gptr     = (int*)alloc((N_GRAPHS + 1) * 4);
  unsigned short* hA  = (unsigned short*)alloc((size_t)M_PAD * DIM * 2);
  unsigned short* tmp = (unsigned short*)alloc((size_t)M_PAD * DIM * 2);
  unsigned short* zb  = (unsigned short*)alloc((size_t)M_PAD * DIM * 2);
  unsigned short* Wt1 = (unsigned short*)alloc(3 * DIM * DIM * 2);
  unsigned short* Wt2 = (unsigned short*)alloc(3 * DIM * DIM * 2);
  float* sA1    = (float*)alloc(384 * 4);
  float* sB1    = (float*)alloc(384 * 4);
  float* sA2    = (float*)alloc(384 * 4);
  float* sB2    = (float*)alloc(384 * 4);
  float* pooled = (float*)alloc((size_t)N_GRAPHS * 384 * 4);

  // CSR build via bucketed counting sort (edges constant across layers)
  k_zero32<<<(NCOPY * NBUCK + 255) / 256, 256, 0, stream>>>(cnt, NCOPY * NBUCK);
  k_bucket<<<(N_EDGES + 255) / 256, 256, 0, stream>>>(ei, cnt, rec);
  k_bscan<<<1, 512, 0, stream>>>(cnt, bbase, row_ptr);
  k_build<<<NBUCK, 256, 0, stream>>>(rec, cnt, bbase, row_ptr, colb);
  k_gptr<<<9, 64, 0, stream>>>(batch, gptr);

  k_convx<<<(M_PAD * 64 + 255) / 256, 256, 0, stream>>>(x, (unsigned*)hA);
  k_convw<<<(3 * DIM * DIM + 255) / 256, 256, 0, stream>>>(W1, W2, Wt1, Wt2);
  k_coef<<<3, 128, 0, stream>>>(b1, gamma, beta, rmean, rvar, b2, sA1, sB1, sA2, sB2);

  for (int l = 0; l < 3; ++l) {
    k_aggr<<<M_PAD / 4, 256, 0, stream>>>((const unsigned*)hA, row_ptr, colb, (unsigned*)tmp);
    k_gemm<<<M_PAD / 64, 256, 0, stream>>>(tmp, Wt1 + l * DIM * DIM, sA1 + l * DIM, sB1 + l * DIM, zb);
    k_gemm<<<M_PAD / 64, 256, 0, stream>>>(zb, Wt2 + l * DIM * DIM, sA2 + l * DIM, sB2 + l * DIM, hA);
    k_pool<<<N_GRAPHS, 512, 0, stream>>>(hA, gptr, pooled, l);
  }
  k_head<<<N_GRAPHS, 128, 0, stream>>>(pooled, Wfin, bfin, Wout, bout, out);
}

// Round 3
// 875.990 us; speedup vs baseline: 1.3120x; 1.2793x over previous
//
#include <hip/hip_runtime.h>
#include <stdint.h>

#define N_NODES 100000
#define N_EDGES 3200000
#define N_GRAPHS 512
#define DIM 128
#define M_PAD 100096          // N_NODES padded to multiple of 64
#define NBUCK 391             // buckets of 256 dst nodes: 391*256 = 100096 >= 100000
#define CAP 9216              // per-bucket region capacity; mean 8184, sigma ~90
#define TILE 4096             // edges per block in k_bucket
#define NTILE 782             // ceil(3.2M / 4096)

typedef __bf16 bf16x8 __attribute__((ext_vector_type(8)));
typedef float f32x4 __attribute__((ext_vector_type(4)));

__device__ __forceinline__ unsigned short f2bf(float f) {
  unsigned u = __float_as_uint(f);
  u = u + 0x7FFFu + ((u >> 16) & 1u);      // round-to-nearest-even
  return (unsigned short)(u >> 16);
}
__device__ __forceinline__ float bflo(unsigned v) { return __uint_as_float(v << 16); }
__device__ __forceinline__ float bfhi(unsigned v) { return __uint_as_float(v & 0xFFFF0000u); }
__device__ __forceinline__ unsigned packbf(float a, float b) {
  return (unsigned)f2bf(a) | ((unsigned)f2bf(b) << 16);
}

// ---------------- CSR build: tiled-reservation counting sort ----------------
__global__ void k_zero32(int* __restrict__ p, int n) {
  int i = blockIdx.x * 256 + threadIdx.x;
  if (i < n) p[i] = 0;
}

// Pass A: one block per 4096-edge tile. LDS histogram -> one global atomic per
// bucket per tile (391/block, not 1/edge) -> LDS-cursor scatter of records.
__global__ __launch_bounds__(256) void k_bucket(const int* __restrict__ ei,
                                                int* __restrict__ cnt,
                                                unsigned* __restrict__ rec) {
  __shared__ int hist[NBUCK];
  __shared__ int curs[NBUCK];
  int t = threadIdx.x;
  int base_e = blockIdx.x * TILE;
  int es[16], ed[16];
#pragma unroll
  for (int k = 0; k < 16; ++k) {
    int e = base_e + k * 256 + t;
    if (e < N_EDGES) { es[k] = ei[e]; ed[k] = ei[N_EDGES + e]; }
    else ed[k] = -1;
  }
  for (int i = t; i < NBUCK; i += 256) hist[i] = 0;
  __syncthreads();
#pragma unroll
  for (int k = 0; k < 16; ++k)
    if (ed[k] >= 0) atomicAdd(&hist[ed[k] >> 8], 1);
  __syncthreads();
  for (int i = t; i < NBUCK; i += 256) {
    int h = hist[i];
    int g = h ? atomicAdd(&cnt[i], h) : 0;
    curs[i] = i * CAP + g;
  }
  __syncthreads();
#pragma unroll
  for (int k = 0; k < 16; ++k) {
    if (ed[k] >= 0) {
      int b = ed[k] >> 8;
      int pos = atomicAdd(&curs[b], 1);
      rec[pos] = ((unsigned)es[k] << 8) | (unsigned)(ed[k] & 255);
    }
  }
}

// Scan bucket totals -> bucket bases. One block of 512 threads.
__global__ __launch_bounds__(512) void k_bscan(const int* __restrict__ cnt,
                                               int* __restrict__ bbase,
                                               int* __restrict__ row_ptr) {
  __shared__ int sc[512];
  int t = threadIdx.x;
  int tot = (t < NBUCK) ? min(cnt[t], CAP) : 0;
  sc[t] = tot; __syncthreads();
  for (int off = 1; off < 512; off <<= 1) {
    int x = (t >= off) ? sc[t - off] : 0;
    __syncthreads();
    sc[t] += x;
    __syncthreads();
  }
  if (t < NBUCK) bbase[t] = sc[t] - tot;                 // exclusive
  if (t == NBUCK - 1) {
    bbase[NBUCK] = sc[t];
    row_ptr[N_NODES] = sc[t];                            // == N_EDGES
  }
}

// Pass B: per bucket -> LDS histogram + scan -> row_ptr slice + col scatter.
__global__ __launch_bounds__(256) void k_build(const unsigned* __restrict__ rec,
                                               const int* __restrict__ cnt,
                                               const int* __restrict__ bbase,
                                               int* __restrict__ row_ptr,
                                               int* __restrict__ col) {
  __shared__ int hist[256];
  __shared__ int sc[256];
  __shared__ int curs[256];
  int b = blockIdx.x, t = threadIdx.x;
  int n = min(cnt[b], CAP);
  const unsigned* p = rec + (size_t)b * CAP;
  hist[t] = 0; __syncthreads();
  for (int i = t; i < n; i += 256) atomicAdd(&hist[p[i] & 255u], 1);
  __syncthreads();
  int v = hist[t];
  sc[t] = v; __syncthreads();
  for (int off = 1; off < 256; off <<= 1) {
    int x = (t >= off) ? sc[t - off] : 0;
    __syncthreads();
    sc[t] += x;
    __syncthreads();
  }
  int excl = bbase[b] + sc[t] - v;
  int node = (b << 8) + t;
  if (node < N_NODES) row_ptr[node] = excl;
  curs[t] = excl;
  __syncthreads();
  for (int i = t; i < n; i += 256) {
    unsigned w = p[i];
    int pos = atomicAdd(&curs[w & 255u], 1);
    col[pos] = (int)(w >> 8);
  }
}

__global__ void k_gptr(const int* __restrict__ batch, int* __restrict__ gptr) {
  int g = blockIdx.x * 64 + threadIdx.x;
  if (g > N_GRAPHS) return;
  int lo = 0, hi = N_NODES;
  while (lo < hi) { int mid = (lo + hi) >> 1; if (batch[mid] < g) lo = mid + 1; else hi = mid; }
  gptr[g] = lo;
}

// ---------------- conversions / coefficients ----------------
__global__ void k_convx(const float* __restrict__ x, unsigned* __restrict__ h0) {
  int i = blockIdx.x * 256 + threadIdx.x;   // over M_PAD*64 uint (2 bf16 each)
  if (i >= M_PAD * 64) return;
  unsigned v = 0;
  if ((i >> 6) < N_NODES) {
    float2 f = ((const float2*)x)[i];
    v = packbf(f.x, f.y);
  }
  h0[i] = v;
}

__global__ void k_convw(const float* __restrict__ W1, const float* __restrict__ W2,
                        unsigned short* __restrict__ Wt1, unsigned short* __restrict__ Wt2) {
  int i = blockIdx.x * 256 + threadIdx.x;
  if (i >= 3 * DIM * DIM) return;
  int l = i >> 14, rem = i & 16383, k = rem >> 7, n = rem & 127;
  int o = (l << 14) + (n << 7) + k;          // transposed: Wt[l][n][k]
  Wt1[o] = f2bf(W1[i]);
  Wt2[o] = f2bf(W2[i]);
}

__global__ void k_coef(const float* __restrict__ b1, const float* __restrict__ gamma,
                       const float* __restrict__ beta, const float* __restrict__ rmean,
                       const float* __restrict__ rvar, const float* __restrict__ b2,
                       float* __restrict__ sA1, float* __restrict__ sB1,
                       float* __restrict__ sA2, float* __restrict__ sB2) {
  int i = blockIdx.x * 128 + threadIdx.x;
  if (i >= 3 * DIM) return;
  float sa = gamma[i] * rsqrtf(rvar[i] + 1e-5f);
  sA1[i] = sa;
  sB1[i] = fmaf(sa, b1[i] - rmean[i], beta[i]);  // sa*(b1-rmean)+beta
  sA2[i] = 1.0f;
  sB2[i] = b2[i];
}

// ---------------- aggregation: tmp = h + sum_{nbr} h[nbr]  (wave per node) ----------------
__global__ __launch_bounds__(256) void k_aggr(const unsigned* __restrict__ h,
                                              const int* __restrict__ row_ptr,
                                              const int* __restrict__ col,
                                              unsigned* __restrict__ tmp) {
  int wv = (blockIdx.x << 2) + (threadIdx.x >> 6);
  int lane = threadIdx.x & 63;
  if (wv >= M_PAD) return;
  if (wv >= N_NODES) { tmp[wv * 64 + lane] = 0u; return; }
  unsigned self = h[wv * 64 + lane];
  float a0 = bflo(self), a1 = bfhi(self);
  int s = __builtin_amdgcn_readfirstlane(row_ptr[wv]);
  int e = __builtin_amdgcn_readfirstlane(row_ptr[wv + 1]);
  int i = s;
  for (; i + 4 <= e; i += 4) {
    int c0 = __builtin_amdgcn_readfirstlane(col[i]);
    int c1 = __builtin_amdgcn_readfirstlane(col[i + 1]);
    int c2 = __builtin_amdgcn_readfirstlane(col[i + 2]);
    int c3 = __builtin_amdgcn_readfirstlane(col[i + 3]);
    unsigned v0 = h[c0 * 64 + lane];
    unsigned v1 = h[c1 * 64 + lane];
    unsigned v2 = h[c2 * 64 + lane];
    unsigned v3 = h[c3 * 64 + lane];
    a0 += bflo(v0) + bflo(v1) + bflo(v2) + bflo(v3);
    a1 += bfhi(v0) + bfhi(v1) + bfhi(v2) + bfhi(v3);
  }
  for (; i < e; ++i) {
    int c = __builtin_amdgcn_readfirstlane(col[i]);
    unsigned v = h[c * 64 + lane];
    a0 += bflo(v); a1 += bfhi(v);
  }
  tmp[wv * 64 + lane] = packbf(a0, a1);
}

// ---------------- GEMM: out = relu(sA[col] * (A @ W) + sB[col]) in bf16 ----------------
__global__ __launch_bounds__(256) void k_gemm(const unsigned short* __restrict__ A,
                                              const unsigned short* __restrict__ Wt,
                                              const float* __restrict__ sA,
                                              const float* __restrict__ sB,
                                              unsigned short* __restrict__ out) {
  int w = threadIdx.x >> 6, lane = threadIdx.x & 63;
  int q = lane >> 4, n16 = lane & 15;
  int r0 = (blockIdx.x << 6) + (w << 4);
  f32x4 acc[8] = {};
#pragma unroll
  for (int ks = 0; ks < 4; ++ks) {
    bf16x8 a = *(const bf16x8*)(A + (size_t)(r0 + n16) * DIM + ks * 32 + q * 8);
#pragma unroll
    for (int c = 0; c < 8; ++c) {
      bf16x8 b = *(const bf16x8*)(Wt + (size_t)((c << 4) + n16) * DIM + ks * 32 + q * 8);
      acc[c] = __builtin_amdgcn_mfma_f32_16x16x32_bf16(a, b, acc[c], 0, 0, 0);
    }
  }
#pragma unroll
  for (int c = 0; c < 8; ++c) {
    int colc = (c << 4) + n16;
    float s = sA[colc], t = sB[colc];
#pragma unroll
    for (int r = 0; r < 4; ++r) {
      float v = fmaf(s, acc[c][r], t);
      v = fmaxf(v, 0.0f);
      out[(size_t)(r0 + (q << 2) + r) * DIM + colc] = f2bf(v);
    }
  }
}

// ---------------- pooling ----------------
__global__ __launch_bounds__(512) void k_pool(const unsigned short* __restrict__ h,
                                              const int* __restrict__ gptr,
                                              float* __restrict__ pooled, int layer) {
  __shared__ float red[4][DIM];
  int g = blockIdx.x;
  int t = threadIdx.x & 127, s4 = threadIdx.x >> 7;
  int beg = gptr[g], end = gptr[g + 1];
  float acc = 0.f;
  for (int r = beg + s4; r < end; r += 4)
    acc += __uint_as_float(((unsigned)h[(size_t)r * DIM + t]) << 16);
  red[s4][t] = acc; __syncthreads();
  if (s4 == 0)
    pooled[g * 384 + layer * DIM + t] = red[0][t] + red[1][t] + red[2][t] + red[3][t];
}

// ---------------- head ----------------
__global__ __launch_bounds__(128) void k_head(const float* __restrict__ pooled,
                                              const float* __restrict__ Wfin,
                                              const float* __restrict__ bfin,
                                              const float* __restrict__ Wout,
                                              const float* __restrict__ bout,
                                              float* __restrict__ out) {
  __shared__ float p[384], hf[384], lg[10];
  __shared__ float lse;
  int g = blockIdx.x, t = threadIdx.x;
  p[t] = pooled[g * 384 + t];
  p[t + 128] = pooled[g * 384 + 128 + t];
  p[t + 256] = pooled[g * 384 + 256 + t];
  __syncthreads();
#pragma unroll
  for (int jj = 0; jj < 3; ++jj) {
    int j = t + jj * 128;
    float acc = bfin[j];
    for (int k = 0; k < 384; ++k) acc = fmaf(p[k], Wfin[k * 384 + j], acc);
    hf[j] = fmaxf(acc, 0.f);
  }
  __syncthreads();
  if (t < 10) {
    float acc = bout[t];
    for (int k = 0; k < 384; ++k) acc = fmaf(hf[k], Wout[k * 10 + t], acc);
    lg[t] = acc;
  }
  __syncthreads();
  if (t == 0) {
    float m = lg[0];
    for (int i = 1; i < 10; ++i) m = fmaxf(m, lg[i]);
    float ss = 0.f;
    for (int i = 0; i < 10; ++i) ss += expf(lg[i] - m);
    lse = m + logf(ss);
  }
  __syncthreads();
  if (t < 10) {
    out[g * 10 + t] = lg[t];
    out[N_GRAPHS * 10 + g * 10 + t] = lg[t] - lse;
  }
}

extern "C" void kernel_launch(void* const* d_in, const int* in_sizes, int n_in,
                              void* d_out, int out_size, void* d_ws, size_t ws_size,
                              hipStream_t stream) {
  const float* x     = (const float*)d_in[0];
  const int*   ei    = (const int*)d_in[1];    // [2, N_EDGES]: src then dst
  const int*   batch = (const int*)d_in[2];
  const float* W1    = (const float*)d_in[4];
  const float* b1    = (const float*)d_in[5];
  const float* gamma = (const float*)d_in[6];
  const float* beta  = (const float*)d_in[7];
  const float* rmean = (const float*)d_in[8];
  const float* rvar  = (const float*)d_in[9];
  const float* W2    = (const float*)d_in[10];
  const float* b2    = (const float*)d_in[11];
  const float* Wfin  = (const float*)d_in[12];
  const float* bfin  = (const float*)d_in[13];
  const float* Wout  = (const float*)d_in[14];
  const float* bout  = (const float*)d_in[15];
  float* out = (float*)d_out;

  char* p = (char*)d_ws;
  auto alloc = [&](size_t bytes) { char* r = p; p += (bytes + 255) & ~255ull; return r; };
  int* cnt      = (int*)alloc(NBUCK * 4);
  unsigned* rec = (unsigned*)alloc((size_t)NBUCK * CAP * 4);
  int* bbase    = (int*)alloc((NBUCK + 1) * 4);
  int* row_ptr  = (int*)alloc((N_NODES + 1) * 4);
  int* colb     = (int*)alloc((size_t)N_EDGES * 4);
  int* gptr     = (int*)alloc((N_GRAPHS + 1) * 4);
  unsigned short* hA  = (unsigned short*)alloc((size_t)M_PAD * DIM * 2);
  unsigned short* tmp = (unsigned short*)alloc((size_t)M_PAD * DIM * 2);
  unsigned short* zb  = (unsigned short*)alloc((size_t)M_PAD * DIM * 2);
  unsigned short* Wt1 = (unsigned short*)alloc(3 * DIM * DIM * 2);
  unsigned short* Wt2 = (unsigned short*)alloc(3 * DIM * DIM * 2);
  float* sA1    = (float*)alloc(384 * 4);
  float* sB1    = (float*)alloc(384 * 4);
  float* sA2    = (float*)alloc(384 * 4);
  float* sB2    = (float*)alloc(384 * 4);
  float* pooled = (float*)alloc((size_t)N_GRAPHS * 384 * 4);

  // CSR build via tiled-reservation counting sort (edges constant across layers)
  k_zero32<<<(NBUCK + 255) / 256, 256, 0, stream>>>(cnt, NBUCK);
  k_bucket<<<NTILE, 256, 0, stream>>>(ei, cnt, rec);
  k_bscan<<<1, 512, 0, stream>>>(cnt, bbase, row_ptr);
  k_build<<<NBUCK, 256, 0, stream>>>(rec, cnt, bbase, row_ptr, colb);
  k_gptr<<<9, 64, 0, stream>>>(batch, gptr);

  k_convx<<<(M_PAD * 64 + 255) / 256, 256, 0, stream>>>(x, (unsigned*)hA);
  k_convw<<<(3 * DIM * DIM + 255) / 256, 256, 0, stream>>>(W1, W2, Wt1, Wt2);
  k_coef<<<3, 128, 0, stream>>>(b1, gamma, beta, rmean, rvar, b2, sA1, sB1, sA2, sB2);

  for (int l = 0; l < 3; ++l) {
    k_aggr<<<M_PAD / 4, 256, 0, stream>>>((const unsigned*)hA, row_ptr, colb, (unsigned*)tmp);
    k_gemm<<<M_PAD / 64, 256, 0, stream>>>(tmp, Wt1 + l * DIM * DIM, sA1 + l * DIM, sB1 + l * DIM, zb);
    k_gemm<<<M_PAD / 64, 256, 0, stream>>>(zb, Wt2 + l * DIM * DIM, sA2 + l * DIM, sB2 + l * DIM, hA);
    k_pool<<<N_GRAPHS, 512, 0, stream>>>(hA, gptr, pooled, l);
  }
  k_head<<<N_GRAPHS, 128, 0, stream>>>(pooled, Wfin, bfin, Wout, bout, out);
}

// Round 4
// 753.093 us; speedup vs baseline: 1.5261x; 1.1632x over previous
//
#include <hip/hip_runtime.h>
#include <stdint.h>

#define N_NODES 100000
#define N_EDGES 3200000
#define N_GRAPHS 512
#define DIM 128
#define M_PAD 100096          // N_NODES padded to multiple of 64
#define NBUCK 391             // buckets of 256 dst nodes: 391*256 = 100096 >= 100000
#define CAP 9216              // per-bucket region capacity; mean 8184, sigma ~90
#define TILE 4096             // edges per block in k_bucket
#define NTILE 782             // ceil(3.2M / 4096)

typedef __bf16 bf16x8 __attribute__((ext_vector_type(8)));
typedef float f32x4 __attribute__((ext_vector_type(4)));

__device__ __forceinline__ unsigned short f2bf(float f) {
  unsigned u = __float_as_uint(f);
  u = u + 0x7FFFu + ((u >> 16) & 1u);      // round-to-nearest-even
  return (unsigned short)(u >> 16);
}
__device__ __forceinline__ float bflo(unsigned v) { return __uint_as_float(v << 16); }
__device__ __forceinline__ float bfhi(unsigned v) { return __uint_as_float(v & 0xFFFF0000u); }
__device__ __forceinline__ float bfs(unsigned short v) { return __uint_as_float(((unsigned)v) << 16); }
__device__ __forceinline__ unsigned packbf(float a, float b) {
  return (unsigned)f2bf(a) | ((unsigned)f2bf(b) << 16);
}

// ---------------- CSR build: tiled-reservation counting sort ----------------
__global__ void k_zero32(int* __restrict__ p, int n) {
  int i = blockIdx.x * 256 + threadIdx.x;
  if (i < n) p[i] = 0;
}

__global__ __launch_bounds__(256) void k_bucket(const int* __restrict__ ei,
                                                int* __restrict__ cnt,
                                                unsigned* __restrict__ rec) {
  __shared__ int hist[NBUCK];
  __shared__ int curs[NBUCK];
  int t = threadIdx.x;
  int base_e = blockIdx.x * TILE;
  int es[16], ed[16];
#pragma unroll
  for (int k = 0; k < 16; ++k) {
    int e = base_e + k * 256 + t;
    if (e < N_EDGES) { es[k] = ei[e]; ed[k] = ei[N_EDGES + e]; }
    else ed[k] = -1;
  }
  for (int i = t; i < NBUCK; i += 256) hist[i] = 0;
  __syncthreads();
#pragma unroll
  for (int k = 0; k < 16; ++k)
    if (ed[k] >= 0) atomicAdd(&hist[ed[k] >> 8], 1);
  __syncthreads();
  for (int i = t; i < NBUCK; i += 256) {
    int h = hist[i];
    int g = h ? atomicAdd(&cnt[i], h) : 0;
    curs[i] = i * CAP + g;
  }
  __syncthreads();
#pragma unroll
  for (int k = 0; k < 16; ++k) {
    if (ed[k] >= 0) {
      int b = ed[k] >> 8;
      int pos = atomicAdd(&curs[b], 1);
      rec[pos] = ((unsigned)es[k] << 8) | (unsigned)(ed[k] & 255);
    }
  }
}

__global__ __launch_bounds__(512) void k_bscan(const int* __restrict__ cnt,
                                               int* __restrict__ bbase,
                                               int* __restrict__ row_ptr) {
  __shared__ int sc[512];
  int t = threadIdx.x;
  int tot = (t < NBUCK) ? min(cnt[t], CAP) : 0;
  sc[t] = tot; __syncthreads();
  for (int off = 1; off < 512; off <<= 1) {
    int x = (t >= off) ? sc[t - off] : 0;
    __syncthreads();
    sc[t] += x;
    __syncthreads();
  }
  if (t < NBUCK) bbase[t] = sc[t] - tot;                 // exclusive
  if (t == NBUCK - 1) {
    bbase[NBUCK] = sc[t];
    row_ptr[N_NODES] = sc[t];                            // == N_EDGES
  }
}

__global__ __launch_bounds__(256) void k_build(const unsigned* __restrict__ rec,
                                               const int* __restrict__ cnt,
                                               const int* __restrict__ bbase,
                                               int* __restrict__ row_ptr,
                                               int* __restrict__ col) {
  __shared__ int hist[256];
  __shared__ int sc[256];
  __shared__ int curs[256];
  int b = blockIdx.x, t = threadIdx.x;
  int n = min(cnt[b], CAP);
  const unsigned* p = rec + (size_t)b * CAP;
  hist[t] = 0; __syncthreads();
  for (int i = t; i < n; i += 256) atomicAdd(&hist[p[i] & 255u], 1);
  __syncthreads();
  int v = hist[t];
  sc[t] = v; __syncthreads();
  for (int off = 1; off < 256; off <<= 1) {
    int x = (t >= off) ? sc[t - off] : 0;
    __syncthreads();
    sc[t] += x;
    __syncthreads();
  }
  int excl = bbase[b] + sc[t] - v;
  int node = (b << 8) + t;
  if (node < N_NODES) row_ptr[node] = excl;
  curs[t] = excl;
  __syncthreads();
  for (int i = t; i < n; i += 256) {
    unsigned w = p[i];
    int pos = atomicAdd(&curs[w & 255u], 1);
    col[pos] = (int)(w >> 8);
  }
}

// ---------------- conversions / coefficients ----------------
__global__ void k_convx(const float* __restrict__ x, unsigned* __restrict__ h0) {
  int i = blockIdx.x * 256 + threadIdx.x;   // over M_PAD*64 uint (2 bf16 each)
  if (i >= M_PAD * 64) return;
  unsigned v = 0;
  if ((i >> 6) < N_NODES) {
    float2 f = ((const float2*)x)[i];
    v = packbf(f.x, f.y);
  }
  h0[i] = v;
}

__global__ void k_convw(const float* __restrict__ W1, const float* __restrict__ W2,
                        unsigned short* __restrict__ Wt1, unsigned short* __restrict__ Wt2) {
  int i = blockIdx.x * 256 + threadIdx.x;
  if (i >= 3 * DIM * DIM) return;
  int l = i >> 14, rem = i & 16383, k = rem >> 7, n = rem & 127;
  int o = (l << 14) + (n << 7) + k;          // transposed: Wt[l][n][k]
  Wt1[o] = f2bf(W1[i]);
  Wt2[o] = f2bf(W2[i]);
}

__global__ void k_coef(const float* __restrict__ b1, const float* __restrict__ gamma,
                       const float* __restrict__ beta, const float* __restrict__ rmean,
                       const float* __restrict__ rvar,
                       float* __restrict__ sA1, float* __restrict__ sB1) {
  int i = blockIdx.x * 128 + threadIdx.x;
  if (i >= 3 * DIM) return;
  float sa = gamma[i] * rsqrtf(rvar[i] + 1e-5f);
  sA1[i] = sa;
  sB1[i] = fmaf(sa, b1[i] - rmean[i], beta[i]);  // sa*(b1-rmean)+beta
}

// ---------------- aggregation: tmp = h + sum_{nbr} h[nbr]  (wave per node) ----------------
// col indices are vector-loaded once per 64 and broadcast via v_readlane ->
// SGPR-base gathers, 8 independent row-loads in flight per wave.
__global__ __launch_bounds__(256) void k_aggr(const unsigned* __restrict__ h,
                                              const int* __restrict__ row_ptr,
                                              const int* __restrict__ col,
                                              unsigned* __restrict__ tmp) {
  int wv = (blockIdx.x << 2) + (threadIdx.x >> 6);
  int lane = threadIdx.x & 63;
  if (wv >= M_PAD) return;
  if (wv >= N_NODES) { tmp[wv * 64 + lane] = 0u; return; }
  unsigned self = h[wv * 64 + lane];
  float a0 = bflo(self), a1 = bfhi(self);
  int s = __builtin_amdgcn_readfirstlane(row_ptr[wv]);
  int e = __builtin_amdgcn_readfirstlane(row_ptr[wv + 1]);
  for (int base = s; base < e; base += 64) {
    int n = e - base; if (n > 64) n = 64;
    int cv = (lane < n) ? col[base + lane] : 0;
    int j = 0;
    for (; j + 8 <= n; j += 8) {
      int c0 = __builtin_amdgcn_readlane(cv, j + 0);
      int c1 = __builtin_amdgcn_readlane(cv, j + 1);
      int c2 = __builtin_amdgcn_readlane(cv, j + 2);
      int c3 = __builtin_amdgcn_readlane(cv, j + 3);
      int c4 = __builtin_amdgcn_readlane(cv, j + 4);
      int c5 = __builtin_amdgcn_readlane(cv, j + 5);
      int c6 = __builtin_amdgcn_readlane(cv, j + 6);
      int c7 = __builtin_amdgcn_readlane(cv, j + 7);
      unsigned v0 = h[c0 * 64 + lane];
      unsigned v1 = h[c1 * 64 + lane];
      unsigned v2 = h[c2 * 64 + lane];
      unsigned v3 = h[c3 * 64 + lane];
      unsigned v4 = h[c4 * 64 + lane];
      unsigned v5 = h[c5 * 64 + lane];
      unsigned v6 = h[c6 * 64 + lane];
      unsigned v7 = h[c7 * 64 + lane];
      a0 += bflo(v0) + bflo(v1) + bflo(v2) + bflo(v3)
          + bflo(v4) + bflo(v5) + bflo(v6) + bflo(v7);
      a1 += bfhi(v0) + bfhi(v1) + bfhi(v2) + bfhi(v3)
          + bfhi(v4) + bfhi(v5) + bfhi(v6) + bfhi(v7);
    }
    for (; j < n; ++j) {
      int c = __builtin_amdgcn_readlane(cv, j);
      unsigned v = h[c * 64 + lane];
      a0 += bflo(v); a1 += bfhi(v);
    }
  }
  tmp[wv * 64 + lane] = packbf(a0, a1);
}

// ---------------- fused layer: h = relu(relu(bn(A@W1)) @ W2 + b2), pool ----------------
// Block: 256 thr / 4 waves, 64 rows. z tile staged in LDS between the two GEMMs;
// pooling accumulated per graph segment with one fp32 atomicAdd per (seg,col).
__global__ __launch_bounds__(256) void k_layer(const unsigned short* __restrict__ A,
                                               const unsigned short* __restrict__ Wt1,
                                               const float* __restrict__ sA,
                                               const float* __restrict__ sB,
                                               const unsigned short* __restrict__ Wt2,
                                               const float* __restrict__ b2,
                                               const int* __restrict__ batch,
                                               unsigned short* __restrict__ hout,
                                               float* __restrict__ pooled, int layer) {
  __shared__ unsigned short zt[64][136];   // +8 pad: 272 B row stride (16B-aligned, bank-skewed)
  __shared__ int gid[64];
  int w = threadIdx.x >> 6, lane = threadIdx.x & 63;
  int q = lane >> 4, n16 = lane & 15;
  int r0 = blockIdx.x << 6;
  int rw = r0 + (w << 4);

  // GEMM1: z = relu(sA*(A@W1)+sB)
  f32x4 acc[8] = {};
#pragma unroll
  for (int ks = 0; ks < 4; ++ks) {
    bf16x8 a = *(const bf16x8*)(A + (size_t)(rw + n16) * DIM + ks * 32 + q * 8);
#pragma unroll
    for (int c = 0; c < 8; ++c) {
      bf16x8 b = *(const bf16x8*)(Wt1 + (size_t)((c << 4) + n16) * DIM + ks * 32 + q * 8);
      acc[c] = __builtin_amdgcn_mfma_f32_16x16x32_bf16(a, b, acc[c], 0, 0, 0);
    }
  }
  if (threadIdx.x < 64) {
    int rr = r0 + threadIdx.x;
    gid[threadIdx.x] = (rr < N_NODES) ? batch[rr] : -1;
  }
#pragma unroll
  for (int c = 0; c < 8; ++c) {
    int colc = (c << 4) + n16;
    float s = sA[colc], t = sB[colc];
#pragma unroll
    for (int r = 0; r < 4; ++r) {
      float v = fmaxf(fmaf(s, acc[c][r], t), 0.0f);
      zt[(w << 4) + (q << 2) + r][colc] = f2bf(v);
    }
  }
  __syncthreads();

  // GEMM2: h = relu(z@W2 + b2)
  f32x4 acc2[8] = {};
#pragma unroll
  for (int ks = 0; ks < 4; ++ks) {
    bf16x8 a = *(const bf16x8*)(&zt[(w << 4) + n16][ks * 32 + q * 8]);
#pragma unroll
    for (int c = 0; c < 8; ++c) {
      bf16x8 b = *(const bf16x8*)(Wt2 + (size_t)((c << 4) + n16) * DIM + ks * 32 + q * 8);
      acc2[c] = __builtin_amdgcn_mfma_f32_16x16x32_bf16(a, b, acc2[c], 0, 0, 0);
    }
  }
  __syncthreads();   // all zt reads done before overwrite
#pragma unroll
  for (int c = 0; c < 8; ++c) {
    int colc = (c << 4) + n16;
    float t = b2[colc];
#pragma unroll
    for (int r = 0; r < 4; ++r) {
      float v = fmaxf(acc2[c][r] + t, 0.0f);
      unsigned short hv = f2bf(v);
      int rl = (w << 4) + (q << 2) + r;
      zt[rl][colc] = hv;
      hout[(size_t)(r0 + rl) * DIM + colc] = hv;   // pad rows: harmless garbage
    }
  }
  __syncthreads();

  // pooling: segment-accumulate rows of same graph, one atomic per segment
  int colp = threadIdx.x & 127, half = threadIdx.x >> 7;
  int rstart = half << 5;
  float pacc = 0.f;
  int gcur = gid[rstart];
  for (int r = rstart; r < rstart + 32; ++r) {
    int g = gid[r];
    if (g != gcur) {
      if (gcur >= 0) atomicAdd(&pooled[gcur * 384 + layer * DIM + colp], pacc);
      pacc = 0.f; gcur = g;
    }
    if (g >= 0) pacc += bfs(zt[r][colp]);
  }
  if (gcur >= 0) atomicAdd(&pooled[gcur * 384 + layer * DIM + colp], pacc);
}

// ---------------- head: 8 graphs per block ----------------
__global__ __launch_bounds__(384) void k_head(const float* __restrict__ pooled,
                                              const float* __restrict__ Wfin,
                                              const float* __restrict__ bfin,
                                              const float* __restrict__ Wout,
                                              const float* __restrict__ bout,
                                              float* __restrict__ out) {
  __shared__ float p[8][384];
  __shared__ float hf[8][392];
  __shared__ float lg[8][10];
  __shared__ float lse[8];
  int t = threadIdx.x, g0 = blockIdx.x << 3;
  for (int i = t; i < 8 * 384; i += 384)
    p[i / 384][i % 384] = pooled[(size_t)(g0 + i / 384) * 384 + (i % 384)];
  __syncthreads();
  float bb = bfin[t];
  float acc[8];
#pragma unroll
  for (int g = 0; g < 8; ++g) acc[g] = bb;
  for (int k = 0; k < 384; ++k) {
    float wv = Wfin[k * 384 + t];
#pragma unroll
    for (int g = 0; g < 8; ++g) acc[g] = fmaf(p[g][k], wv, acc[g]);
  }
#pragma unroll
  for (int g = 0; g < 8; ++g) hf[g][t] = fmaxf(acc[g], 0.f);
  __syncthreads();
  if (t < 80) {
    int g = t / 10, c = t % 10;
    float a = bout[c];
    for (int k = 0; k < 384; ++k) a = fmaf(hf[g][k], Wout[k * 10 + c], a);
    lg[g][c] = a;
  }
  __syncthreads();
  if (t < 8) {
    float m = lg[t][0];
#pragma unroll
    for (int i = 1; i < 10; ++i) m = fmaxf(m, lg[t][i]);
    float ss = 0.f;
#pragma unroll
    for (int i = 0; i < 10; ++i) ss += __expf(lg[t][i] - m);
    lse[t] = m + __logf(ss);
  }
  __syncthreads();
  if (t < 80) {
    int g = t / 10, c = t % 10;
    out[(size_t)(g0 + g) * 10 + c] = lg[g][c];
    out[(size_t)N_GRAPHS * 10 + (size_t)(g0 + g) * 10 + c] = lg[g][c] - lse[g];
  }
}

extern "C" void kernel_launch(void* const* d_in, const int* in_sizes, int n_in,
                              void* d_out, int out_size, void* d_ws, size_t ws_size,
                              hipStream_t stream) {
  const float* x     = (const float*)d_in[0];
  const int*   ei    = (const int*)d_in[1];    // [2, N_EDGES]: src then dst
  const int*   batch = (const int*)d_in[2];
  const float* W1    = (const float*)d_in[4];
  const float* b1    = (const float*)d_in[5];
  const float* gamma = (const float*)d_in[6];
  const float* beta  = (const float*)d_in[7];
  const float* rmean = (const float*)d_in[8];
  const float* rvar  = (const float*)d_in[9];
  const float* W2    = (const float*)d_in[10];
  const float* b2    = (const float*)d_in[11];
  const float* Wfin  = (const float*)d_in[12];
  const float* bfin  = (const float*)d_in[13];
  const float* Wout  = (const float*)d_in[14];
  const float* bout  = (const float*)d_in[15];
  float* out = (float*)d_out;

  char* p = (char*)d_ws;
  auto alloc = [&](size_t bytes) { char* r = p; p += (bytes + 255) & ~255ull; return r; };
  int* cnt      = (int*)alloc(NBUCK * 4);
  unsigned* rec = (unsigned*)alloc((size_t)NBUCK * CAP * 4);
  int* bbase    = (int*)alloc((NBUCK + 1) * 4);
  int* row_ptr  = (int*)alloc((N_NODES + 1) * 4);
  int* colb     = (int*)alloc((size_t)N_EDGES * 4);
  unsigned short* hA  = (unsigned short*)alloc((size_t)M_PAD * DIM * 2);
  unsigned short* tmp = (unsigned short*)alloc((size_t)M_PAD * DIM * 2);
  unsigned short* Wt1 = (unsigned short*)alloc(3 * DIM * DIM * 2);
  unsigned short* Wt2 = (unsigned short*)alloc(3 * DIM * DIM * 2);
  float* sA1    = (float*)alloc(384 * 4);
  float* sB1    = (float*)alloc(384 * 4);
  float* pooled = (float*)alloc((size_t)N_GRAPHS * 384 * 4);

  // CSR build via tiled-reservation counting sort (edges constant across layers)
  k_zero32<<<(NBUCK + 255) / 256, 256, 0, stream>>>(cnt, NBUCK);
  k_zero32<<<(N_GRAPHS * 384 + 255) / 256, 256, 0, stream>>>((int*)pooled, N_GRAPHS * 384);
  k_bucket<<<NTILE, 256, 0, stream>>>(ei, cnt, rec);
  k_bscan<<<1, 512, 0, stream>>>(cnt, bbase, row_ptr);
  k_build<<<NBUCK, 256, 0, stream>>>(rec, cnt, bbase, row_ptr, colb);

  k_convx<<<(M_PAD * 64 + 255) / 256, 256, 0, stream>>>(x, (unsigned*)hA);
  k_convw<<<(3 * DIM * DIM + 255) / 256, 256, 0, stream>>>(W1, W2, Wt1, Wt2);
  k_coef<<<3, 128, 0, stream>>>(b1, gamma, beta, rmean, rvar, sA1, sB1);

  for (int l = 0; l < 3; ++l) {
    k_aggr<<<M_PAD / 4, 256, 0, stream>>>((const unsigned*)hA, row_ptr, colb, (unsigned*)tmp);
    k_layer<<<M_PAD / 64, 256, 0, stream>>>(tmp, Wt1 + l * DIM * DIM, sA1 + l * DIM,
                                            sB1 + l * DIM, Wt2 + l * DIM * DIM,
                                            b2 + l * DIM, batch, hA, pooled, l);
  }
  k_head<<<N_GRAPHS / 8, 384, 0, stream>>>(pooled, Wfin, bfin, Wout, bout, out);
}